// Round 11
// baseline (263.963 us; speedup 1.0000x reference)
//
#include <hip/hip_runtime.h>
#include <math.h>

#define NFILT 64
#define FRAME_STEP 160
#define FRAME_LEN 400
#define WMAX 24            // max nonzero mel-filter span (verified R1-R10)
#define KPAD 416           // 13 K-steps x 32
#define KSTEPS 13
#define NCOLS 528          // 33 N-tiles x 16; col n: bin = n>>1, re/im = n&1
#define NTILES 33
#define PWSTR 280          // LDS power-spectrum row stride (bins, padded)

typedef __attribute__((ext_vector_type(8))) short short8;   // 8 x bf16 fragment
typedef __attribute__((ext_vector_type(4))) float f32x4;    // MFMA accumulator

__device__ __forceinline__ unsigned short f2bf(float f) {   // f32 -> bf16 RNE
    unsigned u = __float_as_uint(f);
    return (unsigned short)((u + 0x7FFFu + ((u >> 16) & 1u)) >> 16);
}
__device__ __forceinline__ float bf2f(unsigned short h) {
    return __uint_as_float(((unsigned)h) << 16);
}

// ---- init kernel: transposed DFT basis Wt[n][k] in bf16 (d_ws, 440KB) ----
// X[b] = sum_k x_k * (cos(2*pi*k*b/512) - i*sin(...)); col 2b = re, 2b+1 = im.
__global__ void build_wt(unsigned short* __restrict__ wt) {
    int tid = blockIdx.x * blockDim.x + threadIdx.x;
    if (tid >= NCOLS * KPAD) return;
    int n = tid / KPAD, k = tid % KPAD;
    int b = n >> 1;
    float v = 0.0f;
    if (k < FRAME_LEN && b < 257) {
        int r = (k * b) & 511;                       // exact integer reduction
        float ang = (float)r * (6.283185307179586f / 512.0f);
        v = (n & 1) ? -sinf(ang) : cosf(ang);
    }
    wt[tid] = f2bf(v);
}

// ---- main: one 64-thread block (1 wave) = 32 frames via MFMA DFT ----
__global__ __launch_bounds__(64) void fbank_mfma(const float* __restrict__ x,
                                                 const float* __restrict__ filters,
                                                 const unsigned short* __restrict__ wt,
                                                 float* __restrict__ out,
                                                 int nf) {
    __shared__ unsigned short pw16[32 * PWSTR];   // bf16 power spectra, 17.5KB

    const int l = threadIdx.x;          // lane; also filter index in mel phase
    const int fbase = blockIdx.x * 32;

    // ---- per-lane mel filter window: batched scan (R4/R6-verified) ----
    int lo = 257;
#pragma unroll 4
    for (int k0 = 0; k0 < 264; k0 += 8) {
        float fv[8];
#pragma unroll
        for (int i = 0; i < 8; i++) {
            int k = k0 + i;
            fv[i] = (k < 257) ? filters[k * NFILT + l] : 0.0f;
        }
#pragma unroll
        for (int i = 0; i < 8; i++) {
            if (fv[i] != 0.0f && lo == 257) lo = k0 + i;
        }
    }
    if (lo > 256) lo = 256;
    float w[WMAX];
#pragma unroll
    for (int i = 0; i < WMAX; i++) {
        int k = lo + i;
        w[i] = (k <= 256) ? filters[k * NFILT + l] : 0.0f;
    }

    // ---- build A fragments in registers: lane holds 8 contiguous samples ----
    // A-frag layout (16x16x32 bf16): row = l&15, k = (l>>4)*8 + j
    const int row = l & 15, jb = l >> 4, col = l & 15;
    short8 afrag[2][KSTEPS];
#pragma unroll
    for (int m = 0; m < 2; m++) {
#pragma unroll
        for (int s = 0; s < KSTEPS; s++) {
            const int frame = fbase + m * 16 + row;
            const int k0 = s * 32 + jb * 8;
            float pre[8];
            if (frame < nf && k0 < FRAME_LEN) {   // k0 multiple of 8 -> <=392
                const long g = (long)frame * FRAME_STEP + k0;
                const float4* p4 = reinterpret_cast<const float4*>(x + g);
                float4 A = p4[0], B = p4[1];
                float prev = (g > 0) ? x[g - 1] : 0.0f;   // pre[0]=x[0]-0.97*0
                pre[0] = fmaf(-0.97f, prev, A.x);
                pre[1] = fmaf(-0.97f, A.x, A.y);
                pre[2] = fmaf(-0.97f, A.y, A.z);
                pre[3] = fmaf(-0.97f, A.z, A.w);
                pre[4] = fmaf(-0.97f, A.w, B.x);
                pre[5] = fmaf(-0.97f, B.x, B.y);
                pre[6] = fmaf(-0.97f, B.y, B.z);
                pre[7] = fmaf(-0.97f, B.z, B.w);
            } else {
#pragma unroll
                for (int j = 0; j < 8; j++) pre[j] = 0.0f;
            }
            short8 f;
#pragma unroll
            for (int j = 0; j < 8; j++) f[j] = (short)f2bf(pre[j]);
            afrag[m][s] = f;
        }
    }

    // ---- DFT GEMM: 33 N-tiles x 13 K-steps x 2 M-subtiles ----
    // B-frag: col = l&15, k = (l>>4)*8 + j -> 16B contiguous in Wt[n][k]
    const float sc = 1.0f / 512.0f;
    for (int t = 0; t < NTILES; t++) {
        f32x4 acc0 = {0.f, 0.f, 0.f, 0.f};
        f32x4 acc1 = {0.f, 0.f, 0.f, 0.f};
        const short8* bp =
            reinterpret_cast<const short8*>(wt + (t * 16 + col) * KPAD) + jb;
#pragma unroll
        for (int s = 0; s < KSTEPS; s++) {
            short8 bfr = bp[s * 4];   // + s*32 bf16 along k
            acc0 = __builtin_amdgcn_mfma_f32_16x16x32_bf16(afrag[0][s], bfr, acc0, 0, 0, 0);
            acc1 = __builtin_amdgcn_mfma_f32_16x16x32_bf16(afrag[1][s], bfr, acc1, 0, 0, 0);
        }
        // power epilogue: C col=lane&15 row=(lane>>4)*4+reg (verified layout);
        // cols 2b/2b+1 = re/im of bin b -> lane-adjacent -> one shfl_xor(1)
        const int b = t * 8 + (col >> 1);
#pragma unroll
        for (int reg = 0; reg < 4; reg++) {
            float p0 = acc0[reg] * acc0[reg];
            p0 += __shfl_xor(p0, 1, 64);
            float p1 = acc1[reg] * acc1[reg];
            p1 += __shfl_xor(p1, 1, 64);
            if ((l & 1) == 0) {
                const int R0 = jb * 4 + reg;
                pw16[R0 * PWSTR + b] = f2bf(p0 * sc);
                pw16[(R0 + 16) * PWSTR + b] = f2bf(p1 * sc);
            }
        }
    }

    asm volatile("s_waitcnt lgkmcnt(0)" ::: "memory");   // wave-local LDS fence

    // ---- sparse mel + per-frame normalize (lane = filter), frames in pairs ----
    for (int fr = 0; fr < 32; fr += 2) {
        float fa = 1e-30f, fb = 1e-30f;
#pragma unroll
        for (int i = 0; i < WMAX; i++) {
            float pa = bf2f(pw16[fr * PWSTR + lo + i]);        // lo+i <= 256
            float pb = bf2f(pw16[(fr + 1) * PWSTR + lo + i]);
            fa = fmaf(w[i], pa, fa);
            fb = fmaf(w[i], pb, fb);
        }
        float sa = fa, sb = fb;
#pragma unroll
        for (int mk = 1; mk < 64; mk <<= 1) {
            sa += __shfl_xor(sa, mk, 64);
            sb += __shfl_xor(sb, mk, 64);
        }
        const float ma = sa * (1.0f / 64.0f), mb = sb * (1.0f / 64.0f);
        const float da = fa - ma, db = fb - mb;
        float qa = da * da, qb = db * db;
#pragma unroll
        for (int mk = 1; mk < 64; mk <<= 1) {
            qa += __shfl_xor(qa, mk, 64);
            qb += __shfl_xor(qb, mk, 64);
        }
        if (fbase + fr < nf)
            out[(long)(fbase + fr) * NFILT + l] = da * rsqrtf(qa * (1.0f / 64.0f));
        if (fbase + fr + 1 < nf)
            out[(long)(fbase + fr + 1) * NFILT + l] = db * rsqrtf(qb * (1.0f / 64.0f));
    }
}

extern "C" void kernel_launch(void* const* d_in, const int* in_sizes, int n_in,
                              void* d_out, int out_size, void* d_ws, size_t ws_size,
                              hipStream_t stream) {
    (void)n_in; (void)in_sizes; (void)ws_size;   // need 528*416*2 = 439,296 B
    const float* x = (const float*)d_in[0];
    const float* filters = (const float*)d_in[1];
    float* out = (float*)d_out;
    unsigned short* wt = (unsigned short*)d_ws;
    const int nf = out_size / NFILT;

    const int wt_elems = NCOLS * KPAD;
    build_wt<<<(wt_elems + 255) / 256, 256, 0, stream>>>(wt);
    const int nb = (nf + 31) / 32;
    fbank_mfma<<<nb, 64, 0, stream>>>(x, filters, wt, out, nf);
}